// Round 2
// baseline (521.693 us; speedup 1.0000x reference)
//
#include <hip/hip_runtime.h>
#include <math.h>

#define DD 192
#define HH 192
#define WW 384
#define WV 575           // W + D - 1
#define NCHUNK 8
#define DPC 24           // 192 / 8
#define TPB 384          // one thread per pixel

// Kernel A: per-(h, d-chunk) partial online-softmax states.
// Each d-plane row (575 floats x 4 channels) is read from HBM exactly once,
// staged in LDS, and serves BOTH the aligned (pass1) and diagonal (pass2)
// accesses. ws layout: [h][chunk][12 fields][WW] floats.
__global__ __launch_bounds__(TPB, 8) void vr_partial(const float* __restrict__ v,
                                                     float* __restrict__ ws) {
    const int t = threadIdx.x;             // pixel w, 0..383
    const int h = blockIdx.x >> 3;
    const int chunk = blockIdx.x & 7;
    const int d0 = chunk * DPC;

    const size_t dstride = (size_t)HH * WV;       // 110400
    const size_t cstride = (size_t)DD * dstride;  // 21196800

    __shared__ float rows[4][WV + 1];             // +1 pad (alignment hygiene)

    float m1 = -INFINITY, l1 = 0.f, a1 = 0.f, c10 = 0.f, c11 = 0.f, c12 = 0.f;
    float m2 = -INFINITY, l2 = 0.f, a2 = 0.f, c20 = 0.f, c21 = 0.f, c22 = 0.f;

    const float* rowbase = v + (size_t)h * WV + (size_t)d0 * dstride;
    for (int i = 0; i < DPC; ++i) {
        const int d = d0 + i;
        const int sh = (DD - 1) - d;              // diagonal shift == disp value
        const float* r = rowbase + (size_t)i * dstride;
        // stage 4 channel rows, contiguous coalesced dword loads
        #pragma unroll
        for (int c = 0; c < 4; ++c) {
            const float* rc = r + (size_t)c * cstride;
            rows[c][t] = rc[t];
            if (t < WV - TPB) rows[c][t + TPB] = rc[t + TPB];   // 191 tail elems
        }
        __syncthreads();

        const float b1  = rows[0][t];
        const float b2  = rows[0][t + sh];
        const float x10 = rows[1][t];
        const float x20 = rows[1][t + sh];
        const float x11 = rows[2][t];
        const float x21 = rows[2][t + sh];
        const float x12 = rows[3][t];
        const float x22 = rows[3][t + sh];
        const float dv = (float)sh;

        float nm = fmaxf(m1, b1);
        float s  = __expf(m1 - nm);
        float pr = __expf(b1 - nm);
        l1  = l1  * s + pr;
        a1  = a1  * s + pr * dv;
        c10 = c10 * s + pr * x10;
        c11 = c11 * s + pr * x11;
        c12 = c12 * s + pr * x12;
        m1 = nm;

        nm = fmaxf(m2, b2);
        s  = __expf(m2 - nm);
        pr = __expf(b2 - nm);
        l2  = l2  * s + pr;
        a2  = a2  * s + pr * dv;
        c20 = c20 * s + pr * x20;
        c21 = c21 * s + pr * x21;
        c22 = c22 * s + pr * x22;
        m2 = nm;

        __syncthreads();                          // protect LDS for next iter
    }

    float* wp = ws + (((size_t)h * NCHUNK + chunk) * 12) * WW + t;
    wp[0 * WW] = m1;  wp[1 * WW] = l1;  wp[2 * WW]  = a1;
    wp[3 * WW] = c10; wp[4 * WW] = c11; wp[5 * WW]  = c12;
    wp[6 * WW] = m2;  wp[7 * WW] = l2;  wp[8 * WW]  = a2;
    wp[9 * WW] = c20; wp[10 * WW] = c21; wp[11 * WW] = c22;
}

// Kernel B: merge the 8 chunk-states per pixel, write final outputs.
__global__ __launch_bounds__(256, 4) void vr_merge(const float* __restrict__ ws,
                                                   float* __restrict__ out) {
    const int pix = blockIdx.x * 256 + threadIdx.x;   // 0 .. 73727
    const int h = pix / WW;
    const int w = pix - h * WW;
    const int HW = HH * WW;

    #pragma unroll
    for (int pass = 0; pass < 2; ++pass) {
        float M = -INFINITY, L = 0.f, A = 0.f, C0 = 0.f, C1 = 0.f, C2 = 0.f;
        #pragma unroll
        for (int ch = 0; ch < NCHUNK; ++ch) {
            const float* q = ws + (((size_t)h * NCHUNK + ch) * 12 + pass * 6) * WW + w;
            const float mm = q[0];
            const float nm = fmaxf(M, mm);
            const float s0 = __expf(M - nm);
            const float s1 = __expf(mm - nm);
            L  = L  * s0 + q[1 * WW] * s1;
            A  = A  * s0 + q[2 * WW] * s1;
            C0 = C0 * s0 + q[3 * WW] * s1;
            C1 = C1 * s0 + q[4 * WW] * s1;
            C2 = C2 * s0 + q[5 * WW] * s1;
            M = nm;
        }
        const float inv = 1.0f / L;
        const int o = h * WW + w;
        out[(pass * 3 + 0) * HW + o] = C0 * inv;
        out[(pass * 3 + 1) * HW + o] = C1 * inv;
        out[(pass * 3 + 2) * HW + o] = C2 * inv;
        out[(6 + pass) * HW + o]     = A * inv;
    }
}

extern "C" void kernel_launch(void* const* d_in, const int* in_sizes, int n_in,
                              void* d_out, int out_size, void* d_ws, size_t ws_size,
                              hipStream_t stream) {
    const float* v = (const float*)d_in[0];
    float* out = (float*)d_out;
    float* ws = (float*)d_ws;    // needs 192*8*12*384*4 B = 28.3 MB
    vr_partial<<<HH * NCHUNK, TPB, 0, stream>>>(v, ws);
    vr_merge<<<(HH * WW) / 256, 256, 0, stream>>>(ws, out);
}